// Round 4
// baseline (3113.283 us; speedup 1.0000x reference)
//
#include <hip/hip_runtime.h>
#include <stdint.h>

#define B_ 64
#define S_ 512
#define K_ 1024
#define H_ 4096
#define C_ 32

typedef float  f32x4  __attribute__((ext_vector_type(4)));
typedef short  bf16x8 __attribute__((ext_vector_type(8)));
typedef unsigned short u16x8 __attribute__((ext_vector_type(8)));
typedef __attribute__((address_space(3))) unsigned int as3u32;
typedef const __attribute__((address_space(1))) unsigned int as1u32;

__device__ __forceinline__ unsigned short f2bf(float f) {
    unsigned u = __builtin_bit_cast(unsigned, f);
    u += 0x7fffu + ((u >> 16) & 1u);   // RNE
    return (unsigned short)(u >> 16);
}

// ---------------------------------------------------------------------------
// cat_ids may arrive as int32 or int64; detect on-device, normalize to i32.
__global__ void fix_cat_kernel(const void* __restrict__ cat_raw, int* __restrict__ cat32) {
    int t = threadIdx.x;                       // 64 threads = 1 wave
    const long long* c64 = (const long long*)cat_raw;
    const int*       c32 = (const int*)cat_raw;
    long long v = (t < 32) ? c64[t] : 0;
    int bad = (t < 32) && (v < 0 || v >= C_);
    unsigned long long m = __ballot(bad);
    if (m == 0ULL) {
        cat32[t] = (int)c64[t];
    } else {
        cat32[t] = c32[t];
    }
}

// ---------------------------------------------------------------------------
// x f32 -> bf16, vectorized 8 elems/thread
__global__ __launch_bounds__(256) void cvt_x_kernel(const float4* __restrict__ x,
                                                    uint4* __restrict__ xb, int n8) {
    int stride = gridDim.x * blockDim.x;
    for (int i = blockIdx.x * blockDim.x + threadIdx.x; i < n8; i += stride) {
        float4 a = x[2 * i], b = x[2 * i + 1];
        uint4 o;
        o.x = (unsigned)f2bf(a.x) | ((unsigned)f2bf(a.y) << 16);
        o.y = (unsigned)f2bf(a.z) | ((unsigned)f2bf(a.w) << 16);
        o.z = (unsigned)f2bf(b.x) | ((unsigned)f2bf(b.y) << 16);
        o.w = (unsigned)f2bf(b.z) | ((unsigned)f2bf(b.w) << 16);
        xb[i] = o;
    }
}

// ---------------------------------------------------------------------------
// W [C][K][H] f32 -> WT [C][H][K] bf16, LDS-tiled 64x64 transpose
__global__ __launch_bounds__(256) void cvt_w_kernel(const float* __restrict__ W,
                                                    unsigned short* __restrict__ WT) {
    __shared__ unsigned short tile[64 * 68];   // [k][n], padded stride 68
    const int nt = blockIdx.x;                 // 64 n-tiles
    const int kt = blockIdx.y;                 // 16 k-tiles
    const int c  = blockIdx.z;                 // 32 categories
    const int t  = threadIdx.x;

    const float* Wp = W + ((size_t)c << 22);
#pragma unroll
    for (int p = 0; p < 4; ++p) {
        int task = p * 256 + t;
        int kr = task >> 4;
        int nc = (task & 15) << 2;
        float4 v = *(const float4*)(Wp + (size_t)(kt * 64 + kr) * H_ + nt * 64 + nc);
        tile[kr * 68 + nc + 0] = f2bf(v.x);
        tile[kr * 68 + nc + 1] = f2bf(v.y);
        tile[kr * 68 + nc + 2] = f2bf(v.z);
        tile[kr * 68 + nc + 3] = f2bf(v.w);
    }
    __syncthreads();

    unsigned short* WTp = WT + ((size_t)c << 22);
#pragma unroll
    for (int q = 0; q < 2; ++q) {
        int task = q * 256 + t;
        int nl = task >> 3;
        int ko = (task & 7) << 3;
        u16x8 o;
#pragma unroll
        for (int j = 0; j < 8; ++j) o[j] = tile[(ko + j) * 68 + nl];
        *(u16x8*)(WTp + (size_t)(nt * 64 + nl) * K_ + kt * 64 + ko) = o;
    }
}

// ---------------------------------------------------------------------------
// Batched GEMM, 256x256 tile, BK=32, 8 waves (2Mx4N), per-wave 128x64.
// NEW this round: 2-deep LDS ring (64 KiB) -> 2 blocks resident per CU.
// Cross-block wave diversity hides LDS bursts, lgkm stalls and the per-block
// epilogue store drain that lockstep barriers can't. Counted waits kept:
// stage tile tt+2 into the CURRENT buf during phase 1 (safe: issued after the
// all-reads-complete barrier), vmcnt(4) at tile end drains only tile tt+1's
// loads (issued ~1 tile earlier) while tt+2's stay in flight.
__global__ __launch_bounds__(512, 4) void gemm2_kernel(
    const unsigned short* __restrict__ xb,   // [B][S][K] bf16
    const unsigned short* __restrict__ WT,   // [C][H][K] bf16
    const float* __restrict__ bias,          // [C][H]
    const int* __restrict__ cat,             // [B]
    float* __restrict__ out)                 // [B][S][H]
{
    extern __shared__ __align__(16) char smem[];   // 2 bufs x (A 16K | B 16K)

    const int t    = threadIdx.x;
    const int lane = t & 63;
    const int w    = t >> 6;            // 0..7
    const int wm   = w >> 2;            // 0..1
    const int wn   = w & 3;             // 0..3
    const int lo   = lane & 15;
    const int hi   = lane >> 4;         // 0..3

    // XCD-aware bijective swizzle (2048 % 8 == 0)
    const int wg = (blockIdx.x & 7) * 256 + (blockIdx.x >> 3);
    const int bn = wg & 15;
    const int bm = (wg >> 4) & 1;
    const int bb = wg >> 5;

    const int c = cat[bb];

    const unsigned short* Ap = xb + (size_t)bb * (S_ * K_) + (size_t)(bm * 256) * K_;
    const unsigned short* Bp = WT + (size_t)c * ((size_t)H_ * K_) + (size_t)(bn * 256) * K_;

    // staging: chunk ch = i*8+w covers rows [ch*16, ch*16+16), 64B per row.
    // linear LDS dest; global source pre-swizzled (m173): logical k-slot =
    // (lane&3) ^ ((row>>2)&3) = (lane&3) ^ hi.
    const int srow  = lane >> 2;
    const int sslot = (lane & 3) ^ hi;
    const char* srcA[2]; const char* srcB[2];
    int offA[2], offB[2];
#pragma unroll
    for (int i = 0; i < 2; ++i) {
        int ch = i * 8 + w;
        int r  = ch * 16 + srow;
        srcA[i] = (const char*)(Ap + (size_t)r * K_ + sslot * 8);
        srcB[i] = (const char*)(Bp + (size_t)r * K_ + sslot * 8);
        offA[i] = ch * 1024;
        offB[i] = 16384 + ch * 1024;
    }

    // fragment read offsets: row stride 64B, swizzled slot = hi ^ ((row>>2)&3)
    const int xslot = (hi ^ ((lo >> 2) & 3)) << 4;
    int aoff[8], boff[4];
#pragma unroll
    for (int mi = 0; mi < 8; ++mi) aoff[mi] = (wm * 128 + mi * 16 + lo) * 64 + xslot;
#pragma unroll
    for (int ni = 0; ni < 4; ++ni) boff[ni] = 16384 + (wn * 64 + ni * 16 + lo) * 64 + xslot;

    f32x4 acc[8][4];
#pragma unroll
    for (int mi = 0; mi < 8; ++mi)
#pragma unroll
        for (int ni = 0; ni < 4; ++ni) acc[mi][ni] = f32x4{0.f, 0.f, 0.f, 0.f};

#define STAGE_A(s_, d_) do {                                                      \
    const int sa__ = (s_);                                                        \
    char* da__ = smem + (d_) * 32768;                                             \
    __builtin_amdgcn_global_load_lds((as1u32*)(srcA[0] + sa__ * 64),              \
                                     (as3u32*)(da__ + offA[0]), 16, 0, 0);        \
    __builtin_amdgcn_global_load_lds((as1u32*)(srcA[1] + sa__ * 64),              \
                                     (as3u32*)(da__ + offA[1]), 16, 0, 0);        \
} while (0)
#define STAGE_B(s_, d_) do {                                                      \
    const int sb__ = (s_);                                                        \
    char* db__ = smem + (d_) * 32768;                                             \
    __builtin_amdgcn_global_load_lds((as1u32*)(srcB[0] + sb__ * 64),              \
                                     (as3u32*)(db__ + offB[0]), 16, 0, 0);        \
    __builtin_amdgcn_global_load_lds((as1u32*)(srcB[1] + sb__ * 64),              \
                                     (as3u32*)(db__ + offB[1]), 16, 0, 0);        \
} while (0)

    // prologue: stage K-tiles 0,1 into bufs 0,1 (8 vmem instrs); wait tile 0
    // landed (vmcnt(4): tile 1's 4 loads stay in flight).
    STAGE_A(0, 0); STAGE_B(0, 0);
    STAGE_A(1, 1); STAGE_B(1, 1);
    asm volatile("s_waitcnt vmcnt(4)" ::: "memory");
    __builtin_amdgcn_s_barrier();

    // main loop invariant at tile-tt entry: tile tt landed, tile tt+1's 4
    // loads outstanding. Phase 1 stages tile tt+2 into buf tt&1 AFTER the
    // all-reads-done barrier (per-wave lgkmcnt(0) before it), then vmcnt(4)
    // drains tile tt+1 while tt+2 stays in flight. Tail wraps into dead slots.
#pragma unroll 2
    for (int tt = 0; tt < 32; ++tt) {
        char* buf = smem + (tt & 1) * 32768;
        const int sN = (tt + 2) & 31, dN = tt & 1;
        bf16x8 av[4], bv[4], aw[4];

        // ---- phase 0: read av[0..3], bv[0..3]; MFMA quadrant mi 0..3
#pragma unroll
        for (int mi = 0; mi < 4; ++mi) av[mi] = *(const bf16x8*)(buf + aoff[mi]);
#pragma unroll
        for (int ni = 0; ni < 4; ++ni) bv[ni] = *(const bf16x8*)(buf + boff[ni]);
        __builtin_amdgcn_s_barrier();
        asm volatile("s_waitcnt lgkmcnt(0)" ::: "memory");
        __builtin_amdgcn_sched_barrier(0);
        __builtin_amdgcn_s_setprio(1);
#pragma unroll
        for (int mi = 0; mi < 4; ++mi)
#pragma unroll
            for (int ni = 0; ni < 4; ++ni)
                acc[mi][ni] = __builtin_amdgcn_mfma_f32_16x16x32_bf16(
                    bv[ni], av[mi], acc[mi][ni], 0, 0, 0);
        __builtin_amdgcn_s_setprio(0);
        __builtin_amdgcn_s_barrier();

        // ---- phase 1: read aw[0..3] (mi 4..7); all-reads barrier; stage
        //      tile tt+2 into this buf; MFMA quadrant mi 4..7
#pragma unroll
        for (int mi = 0; mi < 4; ++mi) aw[mi] = *(const bf16x8*)(buf + aoff[mi + 4]);
        asm volatile("s_waitcnt lgkmcnt(0)" ::: "memory");
        __builtin_amdgcn_sched_barrier(0);
        __builtin_amdgcn_s_barrier();
        STAGE_A(sN, dN);
        STAGE_B(sN, dN);
        __builtin_amdgcn_s_setprio(1);
#pragma unroll
        for (int mi = 0; mi < 4; ++mi)
#pragma unroll
            for (int ni = 0; ni < 4; ++ni)
                acc[mi + 4][ni] = __builtin_amdgcn_mfma_f32_16x16x32_bf16(
                    bv[ni], aw[mi], acc[mi + 4][ni], 0, 0, 0);
        __builtin_amdgcn_s_setprio(0);
        asm volatile("s_waitcnt vmcnt(4)" ::: "memory");   // counted, never 0
        __builtin_amdgcn_s_barrier();
    }
#undef STAGE_A
#undef STAGE_B

    // drain wrap-staged loads before LDS handoff to the next resident block
    asm volatile("s_waitcnt vmcnt(0)" ::: "memory");

    // epilogue. Operand-swapped D layout: n = frag_base + hi*4 + reg, m = lo.
    // Non-temporal stores: out is write-once, keep B panels in L2.
    float* outp = out + ((size_t)bb * S_ + bm * 256 + wm * 128) * H_ + bn * 256 + wn * 64;
    const float* bp = bias + (size_t)c * H_ + bn * 256 + wn * 64;
#pragma unroll
    for (int ni = 0; ni < 4; ++ni) {
        const int nf = ni * 16 + hi * 4;
        const f32x4 b4 = *(const f32x4*)(bp + nf);
#pragma unroll
        for (int mi = 0; mi < 8; ++mi) {
            const int mf = mi * 16 + lo;
            f32x4 v = acc[mi][ni];
            v.x += b4.x; v.y += b4.y; v.z += b4.z; v.w += b4.w;
            __builtin_nontemporal_store(v, (f32x4*)(outp + (size_t)mf * H_ + nf));
        }
    }
}

// ---------------------------------------------------------------------------
// Fallback (ws too small): correct but slow f32 vector-ALU kernel.
__global__ __launch_bounds__(256) void fallback_kernel(
    const float* __restrict__ x, const int* __restrict__ cat,
    const float* __restrict__ W, const float* __restrict__ bias,
    float* __restrict__ out)
{
    __shared__ float xs[K_];
    int bs = blockIdx.x;
    int bb = bs >> 9;
    int c  = cat[bb];
    const float* xp = x + (size_t)bs * K_;
    for (int i = threadIdx.x; i < K_ / 4; i += 256)
        ((float4*)xs)[i] = ((const float4*)xp)[i];
    __syncthreads();

    int h = blockIdx.y * 1024 + threadIdx.x * 4;
    const float* Wp = W + (size_t)c * K_ * H_ + h;
    float a0 = 0.f, a1 = 0.f, a2 = 0.f, a3 = 0.f;
    for (int k = 0; k < K_; ++k) {
        float xv = xs[k];
        float4 wv = *(const float4*)(Wp + (size_t)k * H_);
        a0 += xv * wv.x; a1 += xv * wv.y; a2 += xv * wv.z; a3 += xv * wv.w;
    }
    float4 bv = *(const float4*)(bias + c * H_ + h);
    float4 o; o.x = a0 + bv.x; o.y = a1 + bv.y; o.z = a2 + bv.z; o.w = a3 + bv.w;
    *(float4*)(out + (size_t)bs * H_ + h) = o;
}

// ---------------------------------------------------------------------------
extern "C" void kernel_launch(void* const* d_in, const int* in_sizes, int n_in,
                              void* d_out, int out_size, void* d_ws, size_t ws_size,
                              hipStream_t stream) {
    const float* x        = (const float*)d_in[0];
    const void*  cat_raw  = d_in[1];
    const float* W        = (const float*)d_in[2];
    const float* bias     = (const float*)d_in[3];
    float*       out      = (float*)d_out;

    const size_t CAT_BYTES = 256;
    const size_t XB_OFF    = 256;
    const size_t XB_BYTES  = (size_t)B_ * S_ * K_ * 2;          // 64 MiB
    const size_t WT_OFF    = XB_OFF + XB_BYTES;
    const size_t WT_BYTES  = (size_t)C_ * H_ * K_ * 2;          // 256 MiB
    const size_t NEED      = WT_OFF + WT_BYTES;

    const int* catp;
    if (ws_size >= CAT_BYTES) {
        int* cat32 = (int*)d_ws;
        fix_cat_kernel<<<1, 64, 0, stream>>>(cat_raw, cat32);
        catp = cat32;
    } else {
        catp = (const int*)cat_raw;
    }

    if (ws_size >= NEED) {
        unsigned short* xb = (unsigned short*)((char*)d_ws + XB_OFF);
        unsigned short* WT = (unsigned short*)((char*)d_ws + WT_OFF);
        cvt_x_kernel<<<2048, 256, 0, stream>>>((const float4*)x, (uint4*)xb,
                                               (int)((size_t)B_ * S_ * K_ / 8));
        dim3 gw(64, 16, 32);
        cvt_w_kernel<<<gw, 256, 0, stream>>>(W, WT);
        hipFuncSetAttribute((const void*)gemm2_kernel,
                            hipFuncAttributeMaxDynamicSharedMemorySize, 65536);
        gemm2_kernel<<<2048, 512, 65536, stream>>>(xb, WT, bias, catp, out);
    } else {
        dim3 g(B_ * S_, H_ / 1024);
        fallback_kernel<<<g, 256, 0, stream>>>(x, catp, W, bias, out);
    }
}

// Round 5
// 566.564 us; speedup vs baseline: 5.4950x; 5.4950x over previous
//
#include <hip/hip_runtime.h>
#include <stdint.h>

#define B_ 64
#define S_ 512
#define K_ 1024
#define H_ 4096
#define C_ 32

typedef float  f32x4  __attribute__((ext_vector_type(4)));
typedef short  bf16x8 __attribute__((ext_vector_type(8)));
typedef unsigned short u16x8 __attribute__((ext_vector_type(8)));
typedef __attribute__((address_space(3))) unsigned int as3u32;
typedef const __attribute__((address_space(1))) unsigned int as1u32;

__device__ __forceinline__ unsigned short f2bf(float f) {
    unsigned u = __builtin_bit_cast(unsigned, f);
    u += 0x7fffu + ((u >> 16) & 1u);   // RNE
    return (unsigned short)(u >> 16);
}

// ---------------------------------------------------------------------------
// cat_ids may arrive as int32 or int64; detect on-device, normalize to i32.
__global__ void fix_cat_kernel(const void* __restrict__ cat_raw, int* __restrict__ cat32) {
    int t = threadIdx.x;                       // 64 threads = 1 wave
    const long long* c64 = (const long long*)cat_raw;
    const int*       c32 = (const int*)cat_raw;
    long long v = (t < 32) ? c64[t] : 0;
    int bad = (t < 32) && (v < 0 || v >= C_);
    unsigned long long m = __ballot(bad);
    if (m == 0ULL) {
        cat32[t] = (int)c64[t];
    } else {
        cat32[t] = c32[t];
    }
}

// ---------------------------------------------------------------------------
// x f32 -> bf16, vectorized 8 elems/thread
__global__ __launch_bounds__(256) void cvt_x_kernel(const float4* __restrict__ x,
                                                    uint4* __restrict__ xb, int n8) {
    int stride = gridDim.x * blockDim.x;
    for (int i = blockIdx.x * blockDim.x + threadIdx.x; i < n8; i += stride) {
        float4 a = x[2 * i], b = x[2 * i + 1];
        uint4 o;
        o.x = (unsigned)f2bf(a.x) | ((unsigned)f2bf(a.y) << 16);
        o.y = (unsigned)f2bf(a.z) | ((unsigned)f2bf(a.w) << 16);
        o.z = (unsigned)f2bf(b.x) | ((unsigned)f2bf(b.y) << 16);
        o.w = (unsigned)f2bf(b.z) | ((unsigned)f2bf(b.w) << 16);
        xb[i] = o;
    }
}

// ---------------------------------------------------------------------------
// W [C][K][H] f32 -> WT [C][H][K] bf16, LDS-tiled 64x64 transpose
__global__ __launch_bounds__(256) void cvt_w_kernel(const float* __restrict__ W,
                                                    unsigned short* __restrict__ WT) {
    __shared__ unsigned short tile[64 * 68];   // [k][n], padded stride 68
    const int nt = blockIdx.x;                 // 64 n-tiles
    const int kt = blockIdx.y;                 // 16 k-tiles
    const int c  = blockIdx.z;                 // 32 categories
    const int t  = threadIdx.x;

    const float* Wp = W + ((size_t)c << 22);
#pragma unroll
    for (int p = 0; p < 4; ++p) {
        int task = p * 256 + t;
        int kr = task >> 4;
        int nc = (task & 15) << 2;
        float4 v = *(const float4*)(Wp + (size_t)(kt * 64 + kr) * H_ + nt * 64 + nc);
        tile[kr * 68 + nc + 0] = f2bf(v.x);
        tile[kr * 68 + nc + 1] = f2bf(v.y);
        tile[kr * 68 + nc + 2] = f2bf(v.z);
        tile[kr * 68 + nc + 3] = f2bf(v.w);
    }
    __syncthreads();

    unsigned short* WTp = WT + ((size_t)c << 22);
#pragma unroll
    for (int q = 0; q < 2; ++q) {
        int task = q * 256 + t;
        int nl = task >> 3;
        int ko = (task & 7) << 3;
        u16x8 o;
#pragma unroll
        for (int j = 0; j < 8; ++j) o[j] = tile[(ko + j) * 68 + nl];
        *(u16x8*)(WTp + (size_t)(nt * 64 + nl) * K_ + kt * 64 + ko) = o;
    }
}

// ---------------------------------------------------------------------------
// PERSISTENT batched GEMM. 256 blocks (1/CU), 8 assignments each.
// Per assignment: 256x256 tile, BK=32, 8 waves (2Mx4N), per-wave 128x64.
// 3-slot LDS ring (96 KiB), stage distance 2, counted vmcnt(4) (never 0
// in-loop), slot XOR-swizzle, setprio around MFMA, 2 phases/tile.
// The ring ROLLS ACROSS assignment boundaries: pipeline fills once per
// kernel; epilogue stores overlap the next assignment's staged tiles.
// Register audit: 128 acc (AGPR) + ~110 VGPR -> 2 waves/SIMD (the cap for
// this tile shape). __launch_bounds__ min-waves MUST stay 2 (round-4 lesson:
// 4 forces a 128-reg budget -> accumulator spill -> 8x regression).
__global__ __launch_bounds__(512, 2) void gemm3_kernel(
    const unsigned short* __restrict__ xb,   // [B][S][K] bf16
    const unsigned short* __restrict__ WT,   // [C][H][K] bf16
    const float* __restrict__ bias,          // [C][H]
    const int* __restrict__ cat,             // [B]
    float* __restrict__ out)                 // [B][S][H]
{
    extern __shared__ __align__(16) char smem[];   // 3 slots x (A 16K | B 16K)

    const int t    = threadIdx.x;
    const int lane = t & 63;
    const int w    = t >> 6;            // 0..7
    const int wm   = w >> 2;            // 0..1
    const int wn   = w & 3;             // 0..3
    const int lo   = lane & 15;
    const int hi   = lane >> 4;         // 0..3

    // persistent work distribution: p -> 8 assignments a = base_a + r.
    // a = xcd*256 + cu*8 + r  (xcd = p&7 matches round-robin dispatch):
    // each CU keeps ONE bn (B-column) and 4 consecutive bb -> B panels stay
    // hot in the XCD L2; A panels served by L3.
    const int p      = blockIdx.x;
    const int base_a = (p & 7) * 256 + (p >> 3) * 8;

    // staging lane geometry: chunk ch = i*8+w covers rows [ch*16, ch*16+16),
    // 64B per row. Linear LDS dest; global source pre-swizzled (m173):
    // logical k-slot = (lane&3) ^ ((row>>2)&3) = (lane&3) ^ hi.
    const int srow  = lane >> 2;
    const int sslot = (lane & 3) ^ hi;
    const size_t rowelem0 = (size_t)((0 * 8 + w) * 16 + srow) * K_ + sslot * 8;
    const size_t rowelem1 = (size_t)((1 * 8 + w) * 16 + srow) * K_ + sslot * 8;
    const int offA0 = (0 * 8 + w) * 1024;
    const int offA1 = (1 * 8 + w) * 1024;
    const int offB0 = 16384 + (0 * 8 + w) * 1024;
    const int offB1 = 16384 + (1 * 8 + w) * 1024;

    // fragment read offsets: row stride 64B, swizzled slot = hi ^ ((row>>2)&3)
    const int xslot = (hi ^ ((lo >> 2) & 3)) << 4;
    int aoff[8], boff[4];
#pragma unroll
    for (int mi = 0; mi < 8; ++mi) aoff[mi] = (wm * 128 + mi * 16 + lo) * 64 + xslot;
#pragma unroll
    for (int ni = 0; ni < 4; ++ni) boff[ni] = 16384 + (wn * 64 + ni * 16 + lo) * 64 + xslot;

    f32x4 acc[8][4];
#pragma unroll
    for (int mi = 0; mi < 8; ++mi)
#pragma unroll
        for (int ni = 0; ni < 4; ++ni) acc[mi][ni] = f32x4{0.f, 0.f, 0.f, 0.f};

    // assignment decode -> per-lane staging bases
#define DECODE(r_, A0_, A1_, B0_, B1_, bn_, bm_, c_) do {                          \
    int a__ = base_a + (r_);                                                       \
    bn_ = a__ >> 7; int bb__ = (a__ >> 1) & 63; bm_ = a__ & 1;                     \
    c_ = cat[bb__];                                                                \
    const unsigned short* Ap__ = xb + (size_t)bb__ * (S_ * K_) + (size_t)(bm_ * 256) * K_; \
    const unsigned short* Bp__ = WT + (size_t)c_ * ((size_t)H_ * K_) + (size_t)(bn_ * 256) * K_; \
    A0_ = (const char*)(Ap__ + rowelem0); A1_ = (const char*)(Ap__ + rowelem1);    \
    B0_ = (const char*)(Bp__ + rowelem0); B1_ = (const char*)(Bp__ + rowelem1);    \
} while (0)

#define GLD(src_, dst_) __builtin_amdgcn_global_load_lds((as1u32*)(src_), (as3u32*)(dst_), 16, 0, 0)

    const char *cA0, *cA1, *cB0, *cB1;   // current assignment staging bases
    const char *nA0, *nA1, *nB0, *nB1;   // next assignment staging bases
    int bn, bm, cc;                      // current assignment decode (epilogue)
    int nbn, nbm, ncc;

    DECODE(0, cA0, cA1, cB0, cB1, bn, bm, cc);

    // prologue (ONCE per kernel): stage global tiles g=0,1 into slots 0,1
    {
        char* d0 = smem;
        char* d1 = smem + 32768;
        GLD(cA0 + 0, d0 + offA0);  GLD(cA1 + 0, d0 + offA1);
        GLD(cB0 + 0, d0 + offB0);  GLD(cB1 + 0, d0 + offB1);
        GLD(cA0 + 64, d1 + offA0); GLD(cA1 + 64, d1 + offA1);
        GLD(cB0 + 64, d1 + offB0); GLD(cB1 + 64, d1 + offB1);
    }
    asm volatile("s_waitcnt vmcnt(4)" ::: "memory");   // tile 0 landed
    __builtin_amdgcn_s_barrier();

    int rs = 0;   // read slot  (= g mod 3)
    int ws = 2;   // write slot (= (g+2) mod 3)

    for (int r = 0; r < 8; ++r) {
        const int rn = (r < 7) ? (r + 1) : 7;
        DECODE(rn, nA0, nA1, nB0, nB1, nbn, nbm, ncc);

        for (int tt = 0; tt < 32; ++tt) {
            const char* buf = smem + rs * 32768;
            char*       dst = smem + ws * 32768;
            const bool  nx  = (tt >= 30);
            const char* pA0 = nx ? nA0 : cA0;
            const char* pA1 = nx ? nA1 : cA1;
            const char* pB0 = nx ? nB0 : cB0;
            const char* pB1 = nx ? nB1 : cB1;
            const int  soff = (nx ? (tt - 30) : (tt + 2)) * 64;

            bf16x8 av[4], bv[4], aw[4];

            // ---- phase 0: read av[0..3], bv[0..3]; stage A-half of tile g+2
#pragma unroll
            for (int mi = 0; mi < 4; ++mi) av[mi] = *(const bf16x8*)(buf + aoff[mi]);
#pragma unroll
            for (int ni = 0; ni < 4; ++ni) bv[ni] = *(const bf16x8*)(buf + boff[ni]);
            GLD(pA0 + soff, dst + offA0);
            GLD(pA1 + soff, dst + offA1);
            __builtin_amdgcn_s_barrier();
            asm volatile("s_waitcnt lgkmcnt(0)" ::: "memory");
            __builtin_amdgcn_sched_barrier(0);
            __builtin_amdgcn_s_setprio(1);
#pragma unroll
            for (int mi = 0; mi < 4; ++mi)
#pragma unroll
                for (int ni = 0; ni < 4; ++ni)
                    acc[mi][ni] = __builtin_amdgcn_mfma_f32_16x16x32_bf16(
                        bv[ni], av[mi], acc[mi][ni], 0, 0, 0);
            __builtin_amdgcn_s_setprio(0);
            __builtin_amdgcn_s_barrier();

            // ---- phase 1: read aw[0..3] (mi 4..7); stage B-half of tile g+2
#pragma unroll
            for (int mi = 0; mi < 4; ++mi) aw[mi] = *(const bf16x8*)(buf + aoff[mi + 4]);
            GLD(pB0 + soff, dst + offB0);
            GLD(pB1 + soff, dst + offB1);
            __builtin_amdgcn_s_barrier();
            asm volatile("s_waitcnt lgkmcnt(0)" ::: "memory");
            __builtin_amdgcn_sched_barrier(0);
            __builtin_amdgcn_s_setprio(1);
#pragma unroll
            for (int mi = 0; mi < 4; ++mi)
#pragma unroll
                for (int ni = 0; ni < 4; ++ni)
                    acc[mi + 4][ni] = __builtin_amdgcn_mfma_f32_16x16x32_bf16(
                        bv[ni], aw[mi], acc[mi + 4][ni], 0, 0, 0);
            __builtin_amdgcn_s_setprio(0);
            asm volatile("s_waitcnt vmcnt(4)" ::: "memory");   // counted, never 0
            __builtin_amdgcn_s_barrier();

            rs = (rs == 2) ? 0 : rs + 1;
            ws = (ws == 2) ? 0 : ws + 1;
        }

        // ---- epilogue for assignment r (no barrier: overlaps next tiles).
        // D layout (operand-swapped): n = frag + hi*4 + reg, m = lo.
        {
            const int a__ = base_a + r;
            const int bb__ = (a__ >> 1) & 63;
            float* outp = out + ((size_t)bb__ * S_ + bm * 256 + wm * 128) * H_
                        + bn * 256 + wn * 64;
            const float* bp = bias + (size_t)cc * H_ + bn * 256 + wn * 64;
#pragma unroll
            for (int ni = 0; ni < 4; ++ni) {
                const int nf = ni * 16 + hi * 4;
                const f32x4 b4 = *(const f32x4*)(bp + nf);
#pragma unroll
                for (int mi = 0; mi < 8; ++mi) {
                    const int mf = mi * 16 + lo;
                    f32x4 v = acc[mi][ni];
                    v.x += b4.x; v.y += b4.y; v.z += b4.z; v.w += b4.w;
                    __builtin_nontemporal_store(v, (f32x4*)(outp + (size_t)mf * H_ + nf));
                    acc[mi][ni] = f32x4{0.f, 0.f, 0.f, 0.f};
                }
            }
        }

        cA0 = nA0; cA1 = nA1; cB0 = nB0; cB1 = nB1;
        bn = nbn; bm = nbm; cc = ncc;
    }
#undef GLD
#undef DECODE

    asm volatile("s_waitcnt vmcnt(0)" ::: "memory");
}

// ---------------------------------------------------------------------------
// Fallback (ws too small): correct but slow f32 vector-ALU kernel.
__global__ __launch_bounds__(256) void fallback_kernel(
    const float* __restrict__ x, const int* __restrict__ cat,
    const float* __restrict__ W, const float* __restrict__ bias,
    float* __restrict__ out)
{
    __shared__ float xs[K_];
    int bs = blockIdx.x;
    int bb = bs >> 9;
    int c  = cat[bb];
    const float* xp = x + (size_t)bs * K_;
    for (int i = threadIdx.x; i < K_ / 4; i += 256)
        ((float4*)xs)[i] = ((const float4*)xp)[i];
    __syncthreads();

    int h = blockIdx.y * 1024 + threadIdx.x * 4;
    const float* Wp = W + (size_t)c * K_ * H_ + h;
    float a0 = 0.f, a1 = 0.f, a2 = 0.f, a3 = 0.f;
    for (int k = 0; k < K_; ++k) {
        float xv = xs[k];
        float4 wv = *(const float4*)(Wp + (size_t)k * H_);
        a0 += xv * wv.x; a1 += xv * wv.y; a2 += xv * wv.z; a3 += xv * wv.w;
    }
    float4 bv = *(const float4*)(bias + c * H_ + h);
    float4 o; o.x = a0 + bv.x; o.y = a1 + bv.y; o.z = a2 + bv.z; o.w = a3 + bv.w;
    *(float4*)(out + (size_t)bs * H_ + h) = o;
}

// ---------------------------------------------------------------------------
extern "C" void kernel_launch(void* const* d_in, const int* in_sizes, int n_in,
                              void* d_out, int out_size, void* d_ws, size_t ws_size,
                              hipStream_t stream) {
    const float* x        = (const float*)d_in[0];
    const void*  cat_raw  = d_in[1];
    const float* W        = (const float*)d_in[2];
    const float* bias     = (const float*)d_in[3];
    float*       out      = (float*)d_out;

    const size_t CAT_BYTES = 256;
    const size_t XB_OFF    = 256;
    const size_t XB_BYTES  = (size_t)B_ * S_ * K_ * 2;          // 64 MiB
    const size_t WT_OFF    = XB_OFF + XB_BYTES;
    const size_t WT_BYTES  = (size_t)C_ * H_ * K_ * 2;          // 256 MiB
    const size_t NEED      = WT_OFF + WT_BYTES;

    const int* catp;
    if (ws_size >= CAT_BYTES) {
        int* cat32 = (int*)d_ws;
        fix_cat_kernel<<<1, 64, 0, stream>>>(cat_raw, cat32);
        catp = cat32;
    } else {
        catp = (const int*)cat_raw;
    }

    if (ws_size >= NEED) {
        unsigned short* xb = (unsigned short*)((char*)d_ws + XB_OFF);
        unsigned short* WT = (unsigned short*)((char*)d_ws + WT_OFF);
        cvt_x_kernel<<<2048, 256, 0, stream>>>((const float4*)x, (uint4*)xb,
                                               (int)((size_t)B_ * S_ * K_ / 8));
        dim3 gw(64, 16, 32);
        cvt_w_kernel<<<gw, 256, 0, stream>>>(W, WT);
        hipFuncSetAttribute((const void*)gemm3_kernel,
                            hipFuncAttributeMaxDynamicSharedMemorySize, 98304);
        gemm3_kernel<<<256, 512, 98304, stream>>>(xb, WT, bias, catp, out);
    } else {
        dim3 g(B_ * S_, H_ / 1024);
        fallback_kernel<<<g, 256, 0, stream>>>(x, catp, W, bias, out);
    }
}

// Round 6
// 541.072 us; speedup vs baseline: 5.7539x; 1.0471x over previous
//
#include <hip/hip_runtime.h>
#include <stdint.h>

#define B_ 64
#define S_ 512
#define K_ 1024
#define H_ 4096
#define C_ 32

typedef float  f32x4  __attribute__((ext_vector_type(4)));
typedef short  bf16x8 __attribute__((ext_vector_type(8)));
typedef unsigned short u16x8 __attribute__((ext_vector_type(8)));
typedef __attribute__((address_space(3))) unsigned int as3u32;
typedef const __attribute__((address_space(1))) unsigned int as1u32;

__device__ __forceinline__ unsigned short f2bf(float f) {
    unsigned u = __builtin_bit_cast(unsigned, f);
    u += 0x7fffu + ((u >> 16) & 1u);   // RNE
    return (unsigned short)(u >> 16);
}

// ---------------------------------------------------------------------------
// cat_ids may arrive as int32 or int64; detect on-device, normalize to i32.
__global__ void fix_cat_kernel(const void* __restrict__ cat_raw, int* __restrict__ cat32) {
    int t = threadIdx.x;                       // 64 threads = 1 wave
    const long long* c64 = (const long long*)cat_raw;
    const int*       c32 = (const int*)cat_raw;
    long long v = (t < 32) ? c64[t] : 0;
    int bad = (t < 32) && (v < 0 || v >= C_);
    unsigned long long m = __ballot(bad);
    if (m == 0ULL) {
        cat32[t] = (int)c64[t];
    } else {
        cat32[t] = c32[t];
    }
}

// ---------------------------------------------------------------------------
// x f32 -> bf16, vectorized 8 elems/thread
__global__ __launch_bounds__(256) void cvt_x_kernel(const float4* __restrict__ x,
                                                    uint4* __restrict__ xb, int n8) {
    int stride = gridDim.x * blockDim.x;
    for (int i = blockIdx.x * blockDim.x + threadIdx.x; i < n8; i += stride) {
        float4 a = x[2 * i], b = x[2 * i + 1];
        uint4 o;
        o.x = (unsigned)f2bf(a.x) | ((unsigned)f2bf(a.y) << 16);
        o.y = (unsigned)f2bf(a.z) | ((unsigned)f2bf(a.w) << 16);
        o.z = (unsigned)f2bf(b.x) | ((unsigned)f2bf(b.y) << 16);
        o.w = (unsigned)f2bf(b.z) | ((unsigned)f2bf(b.w) << 16);
        xb[i] = o;
    }
}

// ---------------------------------------------------------------------------
// W [C][K][H] f32 -> WT [C][H][K] bf16, LDS-tiled 64x64 transpose
__global__ __launch_bounds__(256) void cvt_w_kernel(const float* __restrict__ W,
                                                    unsigned short* __restrict__ WT) {
    __shared__ unsigned short tile[64 * 68];   // [k][n], padded stride 68
    const int nt = blockIdx.x;                 // 64 n-tiles
    const int kt = blockIdx.y;                 // 16 k-tiles
    const int c  = blockIdx.z;                 // 32 categories
    const int t  = threadIdx.x;

    const float* Wp = W + ((size_t)c << 22);
#pragma unroll
    for (int p = 0; p < 4; ++p) {
        int task = p * 256 + t;
        int kr = task >> 4;
        int nc = (task & 15) << 2;
        float4 v = *(const float4*)(Wp + (size_t)(kt * 64 + kr) * H_ + nt * 64 + nc);
        tile[kr * 68 + nc + 0] = f2bf(v.x);
        tile[kr * 68 + nc + 1] = f2bf(v.y);
        tile[kr * 68 + nc + 2] = f2bf(v.z);
        tile[kr * 68 + nc + 3] = f2bf(v.w);
    }
    __syncthreads();

    unsigned short* WTp = WT + ((size_t)c << 22);
#pragma unroll
    for (int q = 0; q < 2; ++q) {
        int task = q * 256 + t;
        int nl = task >> 3;
        int ko = (task & 7) << 3;
        u16x8 o;
#pragma unroll
        for (int j = 0; j < 8; ++j) o[j] = tile[(ko + j) * 68 + nl];
        *(u16x8*)(WTp + (size_t)(nt * 64 + nl) * K_ + kt * 64 + ko) = o;
    }
}

// ---------------------------------------------------------------------------
// Batched GEMM, m201-geometry 8-phase: 256x256 tile, BK=64, 16 K-tiles,
// 8 waves (2Mx4N, per-wave 128x64), 2 LDS dbufs of 64 KiB, each split into
// K-half regions [A-ks0 | A-ks1 | B-ks0 | B-ks1] (16 KiB each).
// 4 phases per K-tile (= m201's 8 per 2 tiles), each phase:
//   {4-8 x ds_read_b128 || 2 x global_load_lds -> lgkmcnt(0) -> [vmcnt(6)
//    at ph2/ph4] -> s_barrier -> setprio(1) -> 16 MFMA -> setprio(0)}
// Region rotation: during tile T, ph1/ph2 stage tile T+1's ks1 halves into
// the OTHER buf (its previous occupant's ks1 reads finished at T-1 ph4);
// ph3/ph4 stage tile T+2's ks0 halves into the CURRENT buf's ks0 regions
// (their reads finished at ph2; per-wave lgkmcnt(0) BEFORE each barrier
// guarantees all waves' reads drained before any overwrite). Stage lead is
// 5-7 phases; vmcnt(6) twice per tile keeps 3 phases of loads in flight and
// provably covers every read (never drains to 0 in the main loop).
// Conflict-free LDS swizzle (derived for 64-B rows, b128 reads):
//   phys_slot = logical_slot ^ ((row>>1)&3)
// -> every 8-lane group hits all 8 16-B bank-slots exactly once.
__global__ __launch_bounds__(512, 2) void gemm4_kernel(
    const unsigned short* __restrict__ xb,   // [B][S][K] bf16
    const unsigned short* __restrict__ WT,   // [C][H][K] bf16
    const float* __restrict__ bias,          // [C][H]
    const int* __restrict__ cat,             // [B]
    float* __restrict__ out)                 // [B][S][H]
{
    extern __shared__ __align__(16) char smem[];   // 2 x 64K: [Ak0|Ak1|Bk0|Bk1]

    const int t    = threadIdx.x;
    const int lane = t & 63;
    const int w    = t >> 6;            // 0..7
    const int wm   = w >> 2;            // 0..1
    const int wn   = w & 3;             // 0..3
    const int lo   = lane & 15;
    const int hi   = lane >> 4;         // 0..3

    // XCD-aware bijective swizzle (2048 % 8 == 0); round-2 decode (good FETCH)
    const int wg = (blockIdx.x & 7) * 256 + (blockIdx.x >> 3);
    const int bn = wg & 15;
    const int bm = (wg >> 4) & 1;
    const int bb = wg >> 5;

    const int c = cat[bb];

    const unsigned short* Ap = xb + (size_t)bb * (S_ * K_) + (size_t)(bm * 256) * K_;
    const unsigned short* Bp = WT + (size_t)c * ((size_t)H_ * K_) + (size_t)(bn * 256) * K_;

    // staging: each gload covers 16 rows x 64 B; chunks ch = w and 8+w.
    // LDS dest linear (lane -> row base+lane>>2, phys slot lane&3); global
    // source pre-swizzled: logical slot = (lane&3) ^ ((row>>1)&3)
    //                                   = (lane&3) ^ ((lane>>3)&3).
    const int srow  = lane >> 2;
    const int sslot = (lane & 3) ^ ((lane >> 3) & 3);
    const char* sA0 = (const char*)(Ap + (size_t)((0 * 8 + w) * 16 + srow) * K_ + sslot * 8);
    const char* sA1 = (const char*)(Ap + (size_t)((1 * 8 + w) * 16 + srow) * K_ + sslot * 8);
    const char* sB0 = (const char*)(Bp + (size_t)((0 * 8 + w) * 16 + srow) * K_ + sslot * 8);
    const char* sB1 = (const char*)(Bp + (size_t)((1 * 8 + w) * 16 + srow) * K_ + sslot * 8);
    const int dc0 = (0 * 8 + w) * 1024;
    const int dc1 = (1 * 8 + w) * 1024;

    // fragment read offsets: row stride 64 B, phys slot = hi ^ ((row>>1)&3);
    // (row>>1)&3 == (lo>>1)&3 for all frags (16-row frag stride, 64/128-row
    // wave strides are multiples of 4 rows).
    const int xslot = (hi ^ ((lo >> 1) & 3)) << 4;
    int aoff[8], boff[4];
#pragma unroll
    for (int mi = 0; mi < 8; ++mi) aoff[mi] = (wm * 128 + mi * 16 + lo) * 64 + xslot;
#pragma unroll
    for (int ni = 0; ni < 4; ++ni) boff[ni] = 32768 + (wn * 64 + ni * 16 + lo) * 64 + xslot;

    f32x4 acc[8][4];
#pragma unroll
    for (int mi = 0; mi < 8; ++mi)
#pragma unroll
        for (int ni = 0; ni < 4; ++ni) acc[mi][ni] = f32x4{0.f, 0.f, 0.f, 0.f};

#define GLD(src_, dst_) __builtin_amdgcn_global_load_lds((as1u32*)(src_), (as3u32*)(dst_), 16, 0, 0)
    // stage A-ks half j of K-tile tl into buf b_
#define SA(tl_, j_, b_) do {                                                      \
    const int o_ = (tl_) * 128 + (j_) * 64;                                       \
    char* d_ = smem + (b_) * 65536 + (j_) * 16384;                                \
    GLD(sA0 + o_, d_ + dc0); GLD(sA1 + o_, d_ + dc1);                             \
} while (0)
#define SB(tl_, j_, b_) do {                                                      \
    const int o_ = (tl_) * 128 + (j_) * 64;                                       \
    char* d_ = smem + (b_) * 65536 + 32768 + (j_) * 16384;                        \
    GLD(sB0 + o_, d_ + dc0); GLD(sB1 + o_, d_ + dc1);                             \
} while (0)

    // prologue: tile0 all 4 halves + tile1 ks0 halves (12 gloads);
    // vmcnt(8) -> tile0-ks0 (first 4 loads) landed before ph1 reads.
    SA(0, 0, 0); SB(0, 0, 0);
    SA(0, 1, 0); SB(0, 1, 0);
    SA(1, 0, 1); SB(1, 0, 1);
    asm volatile("s_waitcnt vmcnt(8)" ::: "memory");
    __builtin_amdgcn_s_barrier();

#pragma unroll 2
    for (int kt = 0; kt < 16; ++kt) {
        const int   bf = kt & 1;
        const char* rb = smem + bf * 65536;
        const int   s1 = (kt + 1) & 15;       // tail wraps into dead regions
        const int   s2 = (kt + 2) & 15;
        bf16x8 av[4], bv[4], aw[4];

        // ---- ph1: read a[0-3],b[0-3] @ks0; stage A-ks1(kt+1) -> other buf
#pragma unroll
        for (int mi = 0; mi < 4; ++mi) av[mi] = *(const bf16x8*)(rb + aoff[mi]);
#pragma unroll
        for (int ni = 0; ni < 4; ++ni) bv[ni] = *(const bf16x8*)(rb + boff[ni]);
        SA(s1, 1, bf ^ 1);
        asm volatile("s_waitcnt lgkmcnt(0)" ::: "memory");
        __builtin_amdgcn_sched_barrier(0);
        __builtin_amdgcn_s_barrier();
        __builtin_amdgcn_sched_barrier(0);
        __builtin_amdgcn_s_setprio(1);
#pragma unroll
        for (int mi = 0; mi < 4; ++mi)
#pragma unroll
            for (int ni = 0; ni < 4; ++ni)
                acc[mi][ni] = __builtin_amdgcn_mfma_f32_16x16x32_bf16(
                    bv[ni], av[mi], acc[mi][ni], 0, 0, 0);
        __builtin_amdgcn_s_setprio(0);

        // ---- ph2: read a[4-7] @ks0; stage B-ks1(kt+1); counted vmcnt
#pragma unroll
        for (int mi = 0; mi < 4; ++mi) aw[mi] = *(const bf16x8*)(rb + aoff[mi + 4]);
        SB(s1, 1, bf ^ 1);
        asm volatile("s_waitcnt lgkmcnt(0)" ::: "memory");
        __builtin_amdgcn_sched_barrier(0);
        asm volatile("s_waitcnt vmcnt(6)" ::: "memory");
        __builtin_amdgcn_s_barrier();
        __builtin_amdgcn_sched_barrier(0);
        __builtin_amdgcn_s_setprio(1);
#pragma unroll
        for (int mi = 0; mi < 4; ++mi)
#pragma unroll
            for (int ni = 0; ni < 4; ++ni)
                acc[mi + 4][ni] = __builtin_amdgcn_mfma_f32_16x16x32_bf16(
                    bv[ni], aw[mi], acc[mi + 4][ni], 0, 0, 0);
        __builtin_amdgcn_s_setprio(0);

        // ---- ph3: read a[0-3],b[0-3] @ks1; stage A-ks0(kt+2) -> CURRENT buf
        //      (ks0 reads finished at ph2: all waves drained pre-barrier)
#pragma unroll
        for (int mi = 0; mi < 4; ++mi) av[mi] = *(const bf16x8*)(rb + 16384 + aoff[mi]);
#pragma unroll
        for (int ni = 0; ni < 4; ++ni) bv[ni] = *(const bf16x8*)(rb + 16384 + boff[ni]);
        SA(s2, 0, bf);
        asm volatile("s_waitcnt lgkmcnt(0)" ::: "memory");
        __builtin_amdgcn_sched_barrier(0);
        __builtin_amdgcn_s_barrier();
        __builtin_amdgcn_sched_barrier(0);
        __builtin_amdgcn_s_setprio(1);
#pragma unroll
        for (int mi = 0; mi < 4; ++mi)
#pragma unroll
            for (int ni = 0; ni < 4; ++ni)
                acc[mi][ni] = __builtin_amdgcn_mfma_f32_16x16x32_bf16(
                    bv[ni], av[mi], acc[mi][ni], 0, 0, 0);
        __builtin_amdgcn_s_setprio(0);

        // ---- ph4: read a[4-7] @ks1; stage B-ks0(kt+2); counted vmcnt
#pragma unroll
        for (int mi = 0; mi < 4; ++mi) aw[mi] = *(const bf16x8*)(rb + 16384 + aoff[mi + 4]);
        SB(s2, 0, bf);
        asm volatile("s_waitcnt lgkmcnt(0)" ::: "memory");
        __builtin_amdgcn_sched_barrier(0);
        asm volatile("s_waitcnt vmcnt(6)" ::: "memory");
        __builtin_amdgcn_s_barrier();
        __builtin_amdgcn_sched_barrier(0);
        __builtin_amdgcn_s_setprio(1);
#pragma unroll
        for (int mi = 0; mi < 4; ++mi)
#pragma unroll
            for (int ni = 0; ni < 4; ++ni)
                acc[mi + 4][ni] = __builtin_amdgcn_mfma_f32_16x16x32_bf16(
                    bv[ni], aw[mi], acc[mi + 4][ni], 0, 0, 0);
        __builtin_amdgcn_s_setprio(0);
    }
#undef SA
#undef SB
#undef GLD

    // drain wrap-staged loads before block exit
    asm volatile("s_waitcnt vmcnt(0)" ::: "memory");

    // epilogue. Operand-swapped D layout: n = frag_base + hi*4 + reg, m = lo.
    float* outp = out + ((size_t)bb * S_ + bm * 256 + wm * 128) * H_ + bn * 256 + wn * 64;
    const float* bp = bias + (size_t)c * H_ + bn * 256 + wn * 64;
#pragma unroll
    for (int ni = 0; ni < 4; ++ni) {
        const int nf = ni * 16 + hi * 4;
        const f32x4 b4 = *(const f32x4*)(bp + nf);
#pragma unroll
        for (int mi = 0; mi < 8; ++mi) {
            const int mf = mi * 16 + lo;
            f32x4 v = acc[mi][ni];
            v.x += b4.x; v.y += b4.y; v.z += b4.z; v.w += b4.w;
            __builtin_nontemporal_store(v, (f32x4*)(outp + (size_t)mf * H_ + nf));
        }
    }
}

// ---------------------------------------------------------------------------
// Fallback (ws too small): correct but slow f32 vector-ALU kernel.
__global__ __launch_bounds__(256) void fallback_kernel(
    const float* __restrict__ x, const int* __restrict__ cat,
    const float* __restrict__ W, const float* __restrict__ bias,
    float* __restrict__ out)
{
    __shared__ float xs[K_];
    int bs = blockIdx.x;
    int bb = bs >> 9;
    int c  = cat[bb];
    const float* xp = x + (size_t)bs * K_;
    for (int i = threadIdx.x; i < K_ / 4; i += 256)
        ((float4*)xs)[i] = ((const float4*)xp)[i];
    __syncthreads();

    int h = blockIdx.y * 1024 + threadIdx.x * 4;
    const float* Wp = W + (size_t)c * K_ * H_ + h;
    float a0 = 0.f, a1 = 0.f, a2 = 0.f, a3 = 0.f;
    for (int k = 0; k < K_; ++k) {
        float xv = xs[k];
        float4 wv = *(const float4*)(Wp + (size_t)k * H_);
        a0 += xv * wv.x; a1 += xv * wv.y; a2 += xv * wv.z; a3 += xv * wv.w;
    }
    float4 bv = *(const float4*)(bias + c * H_ + h);
    float4 o; o.x = a0 + bv.x; o.y = a1 + bv.y; o.z = a2 + bv.z; o.w = a3 + bv.w;
    *(float4*)(out + (size_t)bs * H_ + h) = o;
}

// ---------------------------------------------------------------------------
extern "C" void kernel_launch(void* const* d_in, const int* in_sizes, int n_in,
                              void* d_out, int out_size, void* d_ws, size_t ws_size,
                              hipStream_t stream) {
    const float* x        = (const float*)d_in[0];
    const void*  cat_raw  = d_in[1];
    const float* W        = (const float*)d_in[2];
    const float* bias     = (const float*)d_in[3];
    float*       out      = (float*)d_out;

    const size_t CAT_BYTES = 256;
    const size_t XB_OFF    = 256;
    const size_t XB_BYTES  = (size_t)B_ * S_ * K_ * 2;          // 64 MiB
    const size_t WT_OFF    = XB_OFF + XB_BYTES;
    const size_t WT_BYTES  = (size_t)C_ * H_ * K_ * 2;          // 256 MiB
    const size_t NEED      = WT_OFF + WT_BYTES;

    const int* catp;
    if (ws_size >= CAT_BYTES) {
        int* cat32 = (int*)d_ws;
        fix_cat_kernel<<<1, 64, 0, stream>>>(cat_raw, cat32);
        catp = cat32;
    } else {
        catp = (const int*)cat_raw;
    }

    if (ws_size >= NEED) {
        unsigned short* xb = (unsigned short*)((char*)d_ws + XB_OFF);
        unsigned short* WT = (unsigned short*)((char*)d_ws + WT_OFF);
        cvt_x_kernel<<<2048, 256, 0, stream>>>((const float4*)x, (uint4*)xb,
                                               (int)((size_t)B_ * S_ * K_ / 8));
        dim3 gw(64, 16, 32);
        cvt_w_kernel<<<gw, 256, 0, stream>>>(W, WT);
        hipFuncSetAttribute((const void*)gemm4_kernel,
                            hipFuncAttributeMaxDynamicSharedMemorySize, 131072);
        gemm4_kernel<<<2048, 512, 131072, stream>>>(xb, WT, bias, catp, out);
    } else {
        dim3 g(B_ * S_, H_ / 1024);
        fallback_kernel<<<g, 256, 0, stream>>>(x, catp, W, bias, out);
    }
}